// Round 6
// baseline (254.821 us; speedup 1.0000x reference)
//
#include <hip/hip_runtime.h>
#include <math.h>

#define N_ 64
#define C_ 8
#define T_ 300
#define V_ 17
#define M_ 12
#define EPSF 1e-6f
#define TAUF 0.35f

typedef float f32x4 __attribute__((ext_vector_type(4)));

// x shape (N,C,T,V,M), strides: C:61200, T:204, V:12, M:1
// ws layout (floats): ws_part[64*10*48] per-(n,tchunk) partial sums
//                     (slot: pos d*12+m at [0,36), s at [36,48)) | ws_A[64*144]

#define TSPLIT 10
#define TCH (T_ / TSPLIT)   // 30 t per block

// ---------------- Kernel 1: partial reduce over a t-chunk (float4 loads) -> private partial slot
__global__ __launch_bounds__(256) void k_reduce(const float* __restrict__ x,
                                                float* __restrict__ ws_part) {
    const int n = blockIdx.x;
    const int by = blockIdx.y;
    const int t0 = by * TCH;
    const int tid = threadIdx.x;
    __shared__ float pos_acc[36];
    __shared__ float s_acc[12];
    if (tid < 36) pos_acc[tid] = 0.f;
    if (tid < 12) s_acc[tid] = 0.f;
    __syncthreads();

    // ---- s part: channel 3, contiguous 30-row chunk = 1530 float4s
    // f = tid + 256k; float base 4f; m_base(k) = (4*(tid+k)) % 12, period 3 in k.
    {
        const f32x4* xs4 = (const f32x4*)(x + ((size_t)(n * C_ + 3) * T_ + t0) * 204);
        f32x4 a0 = {0.f, 0.f, 0.f, 0.f}, a1 = a0, a2 = a0;
        #pragma unroll
        for (int k = 0; k < 6; ++k) {
            int f = tid + 256 * k;
            if (f < TCH * 51) {
                f32x4 v = xs4[f];
                if (k % 3 == 0) a0 += v;
                else if (k % 3 == 1) a1 += v;
                else a2 += v;
            }
        }
        int mb0 = (4 * tid) % 12;            // in {0,4,8}; +c (c<4) never wraps
        int mb1 = (4 * (tid + 1)) % 12;
        int mb2 = (4 * (tid + 2)) % 12;
        #pragma unroll
        for (int c = 0; c < 4; ++c) {
            atomicAdd(&s_acc[mb0 + c], a0[c]);
            atomicAdd(&s_acc[mb1 + c], a1[c]);
            atomicAdd(&s_acc[mb2 + c], a2[c]);
        }
    }

    // ---- pos part: d in 0..2, t in chunk, 6 float4s per (d,t) at float offset 132
    for (int e = tid; e < 3 * TCH * 6; e += 256) {
        int d = e / (TCH * 6);
        int rem = e % (TCH * 6);
        int tt = rem / 6, q = rem % 6;       // q<3: v=11, q>=3: v=12 (same m bucket)
        const f32x4* xp4 = (const f32x4*)(x + ((size_t)(n * C_ + d) * T_ + t0 + tt) * 204 + 132);
        f32x4 v = xp4[q];
        int m0 = (q % 3) * 4;
        atomicAdd(&pos_acc[d * 12 + m0 + 0], v.x);
        atomicAdd(&pos_acc[d * 12 + m0 + 1], v.y);
        atomicAdd(&pos_acc[d * 12 + m0 + 2], v.z);
        atomicAdd(&pos_acc[d * 12 + m0 + 3], v.w);
    }
    __syncthreads();

    float* slot = ws_part + (size_t)(n * TSPLIT + by) * 48;
    if (tid < 36) slot[tid] = pos_acc[tid];
    if (tid < 12) slot[36 + tid] = s_acc[tid];
}

// ---------------- Kernel 2: sum partials, build fused adjacency A (N,12,12)
__global__ __launch_bounds__(64) void k_adj(const float* __restrict__ ws_part,
                                            const float* __restrict__ alpha_logits,
                                            float* __restrict__ ws_A) {
    const int n = blockIdx.x;
    const int tid = threadIdx.x;
    __shared__ float raw[48];
    __shared__ float posx[12], posy[12], posz[12];
    __shared__ float dist[144];
    __shared__ int ord[60];
    __shared__ float p_s[12];
    __shared__ float alpha_s[4];
    __shared__ float w_s;

    if (tid < 48) {
        float a = 0.f;
        #pragma unroll
        for (int j = 0; j < TSPLIT; ++j) a += ws_part[(size_t)(n * TSPLIT + j) * 48 + tid];
        raw[tid] = a;
    }
    __syncthreads();

    const float PSC = 0.5f / (float)T_;          // pos = raw * 0.5/T
    if (tid < 12) {
        posx[tid] = raw[0 * 12 + tid] * PSC;
        posy[tid] = raw[1 * 12 + tid] * PSC;
        posz[tid] = raw[2 * 12 + tid] * PSC;
    }
    if (tid == 0) {
        float l0 = alpha_logits[0], l1 = alpha_logits[1], l2 = alpha_logits[2], l3 = alpha_logits[3];
        float mx = fmaxf(fmaxf(l0, l1), fmaxf(l2, l3));
        float e0 = expf(l0 - mx), e1 = expf(l1 - mx), e2 = expf(l2 - mx), e3 = expf(l3 - mx);
        float s = e0 + e1 + e2 + e3;
        alpha_s[0] = e0 / s; alpha_s[1] = e1 / s; alpha_s[2] = e2 / s; alpha_s[3] = e3 / s;
    }
    if (tid == 1) {
        const float SSC = 1.f / ((float)(T_ * V_) * TAUF);  // s/tau = raw * SSC
        float sv[12];
        float mx = -1e30f;
        #pragma unroll
        for (int m = 0; m < 12; ++m) { sv[m] = raw[36 + m] * SSC; mx = fmaxf(mx, sv[m]); }
        float sum = 0.f;
        #pragma unroll
        for (int m = 0; m < 12; ++m) { sv[m] = expf(sv[m] - mx); sum += sv[m]; }
        float maxp = 0.f;
        #pragma unroll
        for (int m = 0; m < 12; ++m) { sv[m] = sv[m] / sum; p_s[m] = sv[m]; maxp = fmaxf(maxp, sv[m]); }
        float w = (maxp - 1.f / 12.f) / (1.f - 1.f / 12.f + EPSF);
        w_s = fminf(fmaxf(w, 0.f), 1.f);
    }
    __syncthreads();

    for (int e = tid; e < 144; e += 64) {
        int i = e / 12, j = e % 12;
        float dx = posx[i] - posx[j], dy = posy[i] - posy[j], dz = posz[i] - posz[j];
        dist[e] = sqrtf(dx * dx + dy * dy + dz * dz);
    }
    __syncthreads();

    // top-5 nearest per row (stable tie-break: smallest index wins, matches lax.top_k)
    if (tid < 12) {
        int i = tid, mask = 0;
        #pragma unroll
        for (int r = 0; r < 5; ++r) {
            float bd = 1e30f; int bj = -1;
            #pragma unroll
            for (int j = 0; j < 12; ++j) {
                if (!((mask >> j) & 1)) {
                    float dd = dist[i * 12 + j];
                    if (dd < bd) { bd = dd; bj = j; }
                }
            }
            ord[i * 5 + r] = bj; mask |= (1 << bj);
        }
    }
    __syncthreads();

    float w = w_s;
    for (int e = tid; e < 144; e += 64) {
        int i = e / 12, j = e % 12;
        int rank = 5;
        #pragma unroll
        for (int r = 4; r >= 0; --r) if (ord[i * 5 + r] == j) rank = r;
        float diag = (i == j) ? 1.f : 0.f;
        // kNN rows always contain self (dist 0) -> row sum == k+1 exactly
        float aknn = 0.f;
        #pragma unroll
        for (int kk = 0; kk < 4; ++kk) {
            int K = kk + 2;
            float val = ((rank < K) ? 1.f : 0.f) + diag;
            aknn += alpha_s[kk] * val / ((float)(K + 1) + EPSF);
        }
        float pi = p_s[i], pj = p_s[j];
        float di = 12.f * pi + 2.f, dj = 12.f * pj + 2.f;  // ball row sums
        float ab = (pi + pj + diag) * rsqrtf(di + EPSF) * rsqrtf(dj + EPSF);
        ws_A[n * 144 + e] = w * ab + (1.f - w) * aknn;
    }
}

// ---------------- Kernel 3: out = x + scale * (A@root - root), single read, 2 barriers
#define RT 30   // rows (c,t) per block; 2400 % 30 == 0
__global__ __launch_bounds__(256) void k_main(const float* __restrict__ x,
                                              const float* __restrict__ ws_A,
                                              const float* __restrict__ lambda_fuse,
                                              const float* __restrict__ tag_gate,
                                              float* __restrict__ out) {
    const int n = blockIdx.y;
    const int r0 = blockIdx.x * RT;   // row index within n, rows = C*T = 2400
    const int tid = threadIdx.x;
    __shared__ f32x4 xs4[RT * 51];    // 30 rows x 204 floats = 24480 B
    __shared__ float Ash[144];
    __shared__ float delta_sh[RT * 12];
    float* xs = (float*)xs4;

    if (tid < 36) ((f32x4*)Ash)[tid] = ((const f32x4*)(ws_A + n * 144))[tid];
    float scale = tanhf(tag_gate[0]) * lambda_fuse[0];

    const float* xn = x + (size_t)n * 2400 * 204;
    float* on = out + (size_t)n * 2400 * 204;
    const f32x4* x4 = (const f32x4*)(xn + (size_t)r0 * 204);  // r0*204 % 4 == 0
    f32x4* o4 = (f32x4*)(on + (size_t)r0 * 204);

    // Phase A: coalesced single read of the whole tile into LDS
    for (int f = tid; f < RT * 51; f += 256) xs4[f] = x4[f];
    __syncthreads();

    // Phase B: delta = scale * (A@root - root); root read on-the-fly from staged tile
    for (int e = tid; e < RT * 12; e += 256) {
        int r = e / 12, u = e % 12;
        const float* row = xs + r * 204;
        float acc = 0.f;
        #pragma unroll
        for (int v = 0; v < 12; ++v) {
            float rv = 0.5f * (row[132 + v] + row[144 + v]);  // v=11,12 slots
            acc += Ash[u * 12 + v] * rv;
        }
        float ru = 0.5f * (row[132 + u] + row[144 + u]);
        delta_sh[e] = scale * (acc - ru);
    }
    __syncthreads();

    // Phase C: out = lds + delta, nontemporal coalesced store
    for (int f = tid; f < RT * 51; f += 256) {
        int r = f / 51, j = f % 51;
        int m0 = (4 * j) % 12;            // m never wraps inside a float4 (m0 in {0,4,8})
        f32x4 v = xs4[f];
        const float* d = &delta_sh[r * 12 + m0];
        v.x += d[0]; v.y += d[1]; v.z += d[2]; v.w += d[3];
        __builtin_nontemporal_store(v, &o4[f]);
    }
}

extern "C" void kernel_launch(void* const* d_in, const int* in_sizes, int n_in,
                              void* d_out, int out_size, void* d_ws, size_t ws_size,
                              hipStream_t stream) {
    const float* x = (const float*)d_in[0];
    const float* alpha_logits = (const float*)d_in[1];
    const float* lambda_fuse = (const float*)d_in[2];
    const float* tag_gate = (const float*)d_in[3];
    float* out = (float*)d_out;

    float* ws = (float*)d_ws;
    float* ws_part = ws;                      // 64*10*48 floats
    float* ws_A = ws + 64 * TSPLIT * 48;      // 64*144

    k_reduce<<<dim3(N_, TSPLIT), dim3(256), 0, stream>>>(x, ws_part);
    k_adj<<<dim3(N_), dim3(64), 0, stream>>>(ws_part, alpha_logits, ws_A);
    k_main<<<dim3(2400 / RT, N_), dim3(256), 0, stream>>>(x, ws_A, lambda_fuse, tag_gate, out);
}